// Round 3
// baseline (715.566 us; speedup 1.0000x reference)
//
#include <hip/hip_runtime.h>

#define NIMG 16
#define CI   128
#define CO   256
#define HH   128
#define WW   128

typedef short bf16x8 __attribute__((ext_vector_type(8)));
typedef float f32x4  __attribute__((ext_vector_type(4)));

__device__ __forceinline__ unsigned short f2bf(float f) {
    unsigned u = __builtin_bit_cast(unsigned, f);
    unsigned r = u + 0x7fffu + ((u >> 16) & 1u);   // RNE
    return (unsigned short)(r >> 16);
}

__device__ __forceinline__ void gld16(const unsigned short* g, unsigned short* l) {
    __builtin_amdgcn_global_load_lds(
        (const __attribute__((address_space(1))) unsigned int*)g,
        (__attribute__((address_space(3))) unsigned int*)l, 16, 0, 0);
}

// ---------------------------------------------------------------------------
// Prep 1: weights OIHW fp32 -> wt[tap][co][ci] bf16, scaled by kx[i]*kx[j]
// ---------------------------------------------------------------------------
__global__ void xform_w(const float* __restrict__ wsrc, unsigned short* __restrict__ wt) {
    int idx = blockIdx.x * 256 + threadIdx.x;       // (tap*256 + o)*128 + ci
    int ci   = idx & 127;
    int rest = idx >> 7;
    int o    = rest & 255;
    int tap  = rest >> 8;
    int i = tap / 3, j = tap - 3 * i;
    const float s0 = 0.7f;
    float si = (i == 1) ? 1.0f : s0;
    float sj = (j == 1) ? 1.0f : s0;
    float v = wsrc[((o * 128 + ci) * 3 + i) * 3 + j] * si * sj;
    wt[idx] = f2bf(v);
}

// ---------------------------------------------------------------------------
// Prep 2: x NCHW fp32 -> xt[kc][n][130][130][32] bf16, halo pads zeroed.
// Block = one (n, hp) padded row. float4 loads, LDS transpose, int4 stores.
// ---------------------------------------------------------------------------
__global__ __launch_bounds__(256) void xform_x(const float* __restrict__ x,
                                               unsigned short* __restrict__ xt) {
    int bid = blockIdx.x;                // n*130 + hp
    int n = bid / 130, hp = bid - n * 130;
    int t = threadIdx.x;
    __shared__ __align__(16) unsigned short ls[128][136];   // [w][c]

    bool interior = (hp >= 1 && hp <= 128);
    if (interior) {
        int h = hp - 1;
#pragma unroll 4
        for (int it = 0; it < 16; ++it) {
            int idx = it * 256 + t;      // [0,4096): c = idx>>5, w4 = idx&31
            int c = idx >> 5, w4 = idx & 31;
            float4 v = *(const float4*)(x + (((size_t)n * CI + c) * HH + h) * WW + w4 * 4);
            int w = w4 * 4;
            ls[w + 0][c] = f2bf(v.x);
            ls[w + 1][c] = f2bf(v.y);
            ls[w + 2][c] = f2bf(v.z);
            ls[w + 3][c] = f2bf(v.w);
        }
        __syncthreads();
    }
    for (int kc = 0; kc < 4; ++kc) {
        unsigned short* rowbase = xt + ((((size_t)kc * NIMG + n) * 130 + hp) * 130) * 32;
        for (int q = t; q < 520; q += 256) {            // 16B chunks: wp = q>>2, part = q&3
            int wp = q >> 2, part = q & 3;
            int4 v = make_int4(0, 0, 0, 0);
            if (interior && wp >= 1 && wp <= 128)
                v = *(const int4*)&ls[wp - 1][kc * 32 + part * 8];
            *(int4*)(rowbase + q * 8) = v;
        }
    }
}

// ---------------------------------------------------------------------------
// Main: implicit-GEMM conv. Block = 128 px (one (n,h) row) x 256 co.
// 4 waves, wave-tile 64px x 128co (acc[4][8]). Double-buffered LDS staging
// via global_load_lds(16B) of one contiguous 24.9KB halo region per kc.
// ---------------------------------------------------------------------------
__global__ __launch_bounds__(256, 2) void conv_mfma(const unsigned short* __restrict__ xt,
                                                    const unsigned short* __restrict__ wt,
                                                    const float* __restrict__ bias,
                                                    float* __restrict__ out) {
    // XCD swizzle: 256 consecutive logical rows per XCD
    int l = blockIdx.x;                  // [0, 2048)
    int bid = (l & 7) * 256 + (l >> 3);
    int n = bid >> 7, h = bid & 127;
    int tid  = threadIdx.x;
    int lane = tid & 63, wv = tid >> 6;
    int mw = wv & 1, nw = wv >> 1;
    int lr = lane & 15;
    int lq = lane >> 4;

    __shared__ __align__(16) unsigned short xs[2][3 * 130 * 32];  // 2 x 24,960 B
    __shared__ __align__(16) float es[4][16][68];                 // 17,408 B

    // stage kc=0 into buf 0 immediately
    {
        const unsigned short* src = xt + (((size_t)(0 * NIMG + n) * 130 + h) * 130) * 32;
        for (int c = tid; c < 1560; c += 256)
            gld16(src + (size_t)c * 8, &xs[0][c * 8]);
    }

    f32x4 acc[4][8];
    const f32x4 zero = {0.0f, 0.0f, 0.0f, 0.0f};
#pragma unroll
    for (int mi = 0; mi < 4; ++mi)
#pragma unroll
        for (int ni = 0; ni < 8; ++ni) acc[mi][ni] = zero;

    int am[4];
#pragma unroll
    for (int mi = 0; mi < 4; ++mi) am[mi] = (mw * 64 + mi * 16 + lr) * 32 + lq * 8;
    int bo[8];
#pragma unroll
    for (int ni = 0; ni < 8; ++ni) {
        int co = nw * 128 + ni * 16 + lr;
        bo[ni] = co * CI + lq * 8;
    }

#pragma unroll 1
    for (int kc = 0; kc < 4; ++kc) {
        __syncthreads();                 // buf[kc&1] staged (prefetch had full compute phase)
        if (kc < 3) {                    // prefetch next kc into other buffer
            const unsigned short* src =
                xt + ((((size_t)(kc + 1) * NIMG + n) * 130 + h) * 130) * 32;
            unsigned short* dst = &xs[(kc + 1) & 1][0];
            for (int c = tid; c < 1560; c += 256)
                gld16(src + (size_t)c * 8, dst + c * 8);
        }
        const unsigned short* xb = &xs[kc & 1][0];
        const unsigned short* wk = wt + kc * 32;
#pragma unroll
        for (int tap = 0; tap < 9; ++tap) {
            int di = tap / 3, dj = tap - 3 * di;
            int abase = di * (130 * 32) + dj * 32;
            bf16x8 a[4], b[8];
#pragma unroll
            for (int mi = 0; mi < 4; ++mi)
                a[mi] = *(const bf16x8*)(xb + abase + am[mi]);
            const unsigned short* wtap = wk + (size_t)tap * CO * CI;
#pragma unroll
            for (int ni = 0; ni < 8; ++ni)
                b[ni] = *(const bf16x8*)(wtap + bo[ni]);
#pragma unroll
            for (int mi = 0; mi < 4; ++mi)
#pragma unroll
                for (int ni = 0; ni < 8; ++ni)
                    acc[mi][ni] = __builtin_amdgcn_mfma_f32_16x16x32_bf16(
                        a[mi], b[ni], acc[mi][ni], 0, 0, 0);
        }
    }

    // epilogue: LDS transpose -> coalesced NCHW nontemporal stores (+bias)
    for (int ni = 0; ni < 8; ++ni) {
        __syncthreads();
#pragma unroll
        for (int mi = 0; mi < 4; ++mi)
            *(f32x4*)&es[wv][lr][mi * 16 + lq * 4] = acc[mi][ni];
        __syncthreads();
        int row = lane >> 2;             // co-local 0..15
        int cp  = lane & 3;              // w chunk
        int co = nw * 128 + ni * 16 + row;
        float bco = bias[co];
        size_t obase = (((size_t)n * CO + co) * HH + h) * WW + mw * 64 + cp * 16;
#pragma unroll
        for (int q = 0; q < 4; ++q) {
            f32x4 tv = *(const f32x4*)&es[wv][row][cp * 16 + q * 4];
            tv[0] += bco; tv[1] += bco; tv[2] += bco; tv[3] += bco;
            __builtin_nontemporal_store(tv, (f32x4*)(out + obase + q * 4));
        }
    }
}

// ---------------------------------------------------------------------------
// Fallback: direct fp32 conv (only if workspace too small)
// ---------------------------------------------------------------------------
__global__ void conv_direct(const float* __restrict__ x, const float* __restrict__ wsrc,
                            const float* __restrict__ bias, float* __restrict__ out) {
    int b = blockIdx.x;
    int w = threadIdx.x;
    int h = b & 127;
    int rest = b >> 7;
    int o = rest & 255, n = rest >> 8;
    const float s[3] = {0.7f, 1.0f, 0.7f};
    float acc = bias[o];
    for (int ci = 0; ci < 128; ++ci) {
        const float* xp = x + ((size_t)n * CI + ci) * HH * WW;
        const float* wp = wsrc + ((size_t)o * CI + ci) * 9;
        for (int i = 0; i < 3; ++i) {
            int r = h + i - 1;
            if ((unsigned)r >= 128u) continue;
            for (int j = 0; j < 3; ++j) {
                int c = w + j - 1;
                if ((unsigned)c >= 128u) continue;
                acc += xp[r * 128 + c] * wp[i * 3 + j] * s[i] * s[j];
            }
        }
    }
    out[(size_t)b * 128 + w] = acc;
}

extern "C" void kernel_launch(void* const* d_in, const int* in_sizes, int n_in,
                              void* d_out, int out_size, void* d_ws, size_t ws_size,
                              hipStream_t stream) {
    const float* x    = (const float*)d_in[0];
    const float* wsrc = (const float*)d_in[1];
    const float* bias = (const float*)d_in[2];
    float* out = (float*)d_out;

    const size_t wt_bytes = (size_t)9 * CO * CI * 2;                       // 589,824
    const size_t xt_bytes = (size_t)4 * NIMG * 130 * 130 * 32 * 2;         // 69,222,400
    if (ws_size < wt_bytes + xt_bytes) {
        conv_direct<<<NIMG * CO * HH, 128, 0, stream>>>(x, wsrc, bias, out);
        return;
    }
    unsigned short* wt = (unsigned short*)d_ws;
    unsigned short* xt = (unsigned short*)((char*)d_ws + wt_bytes);

    xform_w<<<(9 * CO * CI) / 256, 256, 0, stream>>>(wsrc, wt);
    xform_x<<<NIMG * 130, 256, 0, stream>>>(x, xt);
    conv_mfma<<<NIMG * HH, 256, 0, stream>>>(xt, wt, bias, out);
}